// Round 1
// baseline (963.671 us; speedup 1.0000x reference)
//
#include <hip/hip_runtime.h>
#include <cstddef>
#include <cstdint>

// Problem constants
#define B_   64
#define L_   256
#define E_   128
#define H_   2048
#define C_   256
#define LP_  128      // L/2 after maxpool
#define DI_  512      // d_inner
#define DS_  16       // d_state

typedef __attribute__((ext_vector_type(8))) short s16x8;
typedef __attribute__((ext_vector_type(4))) float f32x4;

// ---------------------------------------------------------------------------
// bf16 split helpers: x = hi + lo, both bf16. Hardware packed convert.
// ---------------------------------------------------------------------------
__device__ __forceinline__ uint32_t cvt_pk_bf16(float a, float b) {
  uint32_t r;
  asm("v_cvt_pk_bf16_f32 %0, %1, %2" : "=v"(r) : "v"(a), "v"(b));
  return r;  // low short = bf16(a), high short = bf16(b)
}

__device__ __forceinline__ void split1(float x, short& h, short& l) {
  uint32_t p = cvt_pk_bf16(x, x);
  float rres = x - __uint_as_float(p << 16);
  uint32_t q = cvt_pk_bf16(rres, rres);
  h = (short)p; l = (short)q;
}

// 8 floats -> hi/lo bf16x8 (6 VALU inst per 2 floats)
__device__ __forceinline__ void cvt8(const float4& a0, const float4& a1,
                                     s16x8& h, s16x8& l) {
  union { uint32_t u[4]; s16x8 v; } H, L;
  float x[8] = {a0.x, a0.y, a0.z, a0.w, a1.x, a1.y, a1.z, a1.w};
#pragma unroll
  for (int j = 0; j < 4; ++j) {
    uint32_t p = cvt_pk_bf16(x[2*j], x[2*j+1]);
    float r0 = x[2*j]   - __uint_as_float(p << 16);
    float r1 = x[2*j+1] - __uint_as_float(p & 0xFFFF0000u);
    H.u[j] = p;
    L.u[j] = cvt_pk_bf16(r0, r1);
  }
  h = H.v; l = L.v;
}

// ---------------------------------------------------------------------------
// embed gather -> pre-split bf16 hi/lo  (e[b,l*E+j] = embed[x[b,l], j])
// ---------------------------------------------------------------------------
__global__ __launch_bounds__(256) void embed_k(const int* __restrict__ x,
                                               const float* __restrict__ emb,
                                               short* __restrict__ ehi,
                                               short* __restrict__ elo) {
  int bl = blockIdx.x * 4 + (threadIdx.x >> 6);
  int lane = threadIdx.x & 63;
  int idx = x[bl];
  float2 v = ((const float2*)(emb + (size_t)idx * E_))[lane];
  uint32_t p = cvt_pk_bf16(v.x, v.y);
  float r0 = v.x - __uint_as_float(p << 16);
  float r1 = v.y - __uint_as_float(p & 0xFFFF0000u);
  uint32_t q = cvt_pk_bf16(r0, r1);
  ((uint32_t*)ehi)[(size_t)bl * 64 + lane] = p;
  ((uint32_t*)elo)[(size_t)bl * 64 + lane] = q;
}

// ---------------------------------------------------------------------------
// one-shot weight preps: conv wT (c,k=t*128+e), in_proj_w, out_proj_w,
// x_proj_w (padded 48->64 rows) -> all pre-split bf16 hi/lo
// ---------------------------------------------------------------------------
__global__ __launch_bounds__(256) void prep_all(
    const float* __restrict__ conv_w, const float* __restrict__ ipw,
    const float* __restrict__ opw,    const float* __restrict__ xpw,
    short* __restrict__ wthi,  short* __restrict__ wtlo,
    short* __restrict__ ipwhi, short* __restrict__ ipwlo,
    short* __restrict__ opwhi, short* __restrict__ opwlo,
    short* __restrict__ xpwhi, short* __restrict__ xpwlo) {
  int blk = blockIdx.x, tid = threadIdx.x;
  if (blk < 640) {                       // conv: k = blk (t*128+e), c = tid
    int k = blk, c = tid, t = k >> 7, e = k & 127;
    float v = conv_w[c * 640 + e * 5 + t];
    short h, l; split1(v, h, l);
    wthi[(size_t)c * 640 + k] = h; wtlo[(size_t)c * 640 + k] = l;
  } else if (blk < 640 + 1024) {         // in_proj_w (1024 x 256)
    int n = blk - 640;
    size_t i = (size_t)n * 256 + tid;
    short h, l; split1(ipw[i], h, l);
    ipwhi[i] = h; ipwlo[i] = l;
  } else if (blk < 640 + 1024 + 512) {   // out_proj_w (256 x 512)
    size_t i = (size_t)(blk - 1664) * 256 + tid;
    short h, l; split1(opw[i], h, l);
    opwhi[i] = h; opwlo[i] = l;
  } else {                               // x_proj_w padded to (64 x 512)
    int i = (blk - 2176) * 256 + tid;    // 0..32767
    int n = i >> 9, k = i & 511;
    float v = (n < 48) ? xpw[n * 512 + k] : 0.0f;
    short h, l; split1(v, h, l);
    xpwhi[i] = h; xpwlo[i] = l;
  }
}

// ---------------------------------------------------------------------------
// MFMA split-bf16 GEMM: C[m,n] = sum_k A[m,k] * W[n,k]
// acc += Ahi*Whi + Ahi*Wlo + Alo*Whi  (3 MFMA per K=32 step)
// BM=BN=64, BK=32, 256 threads = 4 waves, wave tile 16(M)x64(N).
// AM: 0 = f32 A (convert in-kernel), 1 = pre-split bf16 A, 2 = conv gather
//     from pre-split h2 with t-shift + zero pad.
// WM: 0 = f32 W (convert in-kernel), 1 = pre-split bf16 W.
// EPI: 0 = f32 out (+opt bias); 1 = split-K f32 partial; 2 = bias+relu+
//      pre-split out; 3 = conv epilogue bias+relu+maxpool2+pre-split out.
// ---------------------------------------------------------------------------
template<int AM, int WM, int EPI>
__global__ __launch_bounds__(256) void gemm_t(
    const void* __restrict__ Aa, const void* __restrict__ Ab,
    const void* __restrict__ Wa, const void* __restrict__ Wb,
    const float* __restrict__ bias,
    float* __restrict__ Cf, short* __restrict__ Chi, short* __restrict__ Clo,
    int M, int N, int K, int kChunk) {
  // stride 40 shorts = 80 B (16B-aligned rows, <=2-way banks on frag reads)
  __shared__ __align__(16) short AhiS[64][40];
  __shared__ __align__(16) short AloS[64][40];
  __shared__ __align__(16) short WhiS[64][40];
  __shared__ __align__(16) short WloS[64][40];

  const int tid = threadIdx.x;
  const int r   = tid >> 2;                  // staging row 0..63
  const int seg = (tid & 3) * 8;             // staging k-seg 0/8/16/24
  const int lane = tid & 63;
  const int wv   = tid >> 6;                 // wave 0..3 -> M-strip
  const int ml   = lane & 15;
  const int quad = lane >> 4;
  const int bn = blockIdx.x * 64, bm = blockIdx.y * 64;
  const int kStart = blockIdx.z * kChunk, kEnd = kStart + kChunk;

  f32x4 acc[4];
#pragma unroll
  for (int nt = 0; nt < 4; ++nt) acc[nt] = (f32x4){0.f, 0.f, 0.f, 0.f};

  auto loadA = [&](int k0, s16x8& h, s16x8& l) {
    if constexpr (AM == 0) {
      const float* Ar = (const float*)Aa + (size_t)(bm + r) * K + seg + k0;
      float4 a0 = *(const float4*)Ar;
      float4 a1 = *(const float4*)(Ar + 4);
      cvt8(a0, a1, h, l);
    } else if constexpr (AM == 1) {
      size_t o = (size_t)(bm + r) * K + seg + k0;
      h = *(const s16x8*)((const short*)Aa + o);
      l = *(const s16x8*)((const short*)Ab + o);
    } else {  // conv gather from h2 (64 x 256 x 128), k = t*128+e
      int m = bm + r, bb = m >> 8, lrow = m & 255;
      int k = k0 + seg, t = k >> 7, e = k & 127;
      int ls = lrow + t - 2;
      if (ls >= 0 && ls < 256) {
        size_t o = ((size_t)bb << 15) + ((size_t)ls << 7) + (size_t)e;
        h = *(const s16x8*)((const short*)Aa + o);
        l = *(const s16x8*)((const short*)Ab + o);
      } else {
        h = (s16x8)(short)0; l = (s16x8)(short)0;
      }
    }
  };
  auto loadW = [&](int k0, s16x8& h, s16x8& l) {
    if constexpr (WM == 0) {
      const float* Wr = (const float*)Wa + (size_t)(bn + r) * K + seg + k0;
      float4 w0 = *(const float4*)Wr;
      float4 w1 = *(const float4*)(Wr + 4);
      cvt8(w0, w1, h, l);
    } else {
      size_t o = (size_t)(bn + r) * K + seg + k0;
      h = *(const s16x8*)((const short*)Wa + o);
      l = *(const s16x8*)((const short*)Wb + o);
    }
  };

  s16x8 pAh, pAl, pWh, pWl;
  loadA(kStart, pAh, pAl);
  loadW(kStart, pWh, pWl);

  for (int k0 = kStart; k0 < kEnd; k0 += 32) {
    __syncthreads();   // previous iteration's frag reads done
    *(s16x8*)&AhiS[r][seg] = pAh;
    *(s16x8*)&AloS[r][seg] = pAl;
    *(s16x8*)&WhiS[r][seg] = pWh;
    *(s16x8*)&WloS[r][seg] = pWl;
    __syncthreads();
    if (k0 + 32 < kEnd) {                    // prefetch next K-tile
      loadA(k0 + 32, pAh, pAl);
      loadW(k0 + 32, pWh, pWl);
    }
    s16x8 fah = *(const s16x8*)&AhiS[wv * 16 + ml][quad * 8];
    s16x8 fal = *(const s16x8*)&AloS[wv * 16 + ml][quad * 8];
#pragma unroll
    for (int nt = 0; nt < 4; ++nt) {
      s16x8 fwh = *(const s16x8*)&WhiS[nt * 16 + ml][quad * 8];
      s16x8 fwl = *(const s16x8*)&WloS[nt * 16 + ml][quad * 8];
      acc[nt] = __builtin_amdgcn_mfma_f32_16x16x32_bf16(fah, fwh, acc[nt], 0, 0, 0);
      acc[nt] = __builtin_amdgcn_mfma_f32_16x16x32_bf16(fah, fwl, acc[nt], 0, 0, 0);
      acc[nt] = __builtin_amdgcn_mfma_f32_16x16x32_bf16(fal, fwh, acc[nt], 0, 0, 0);
    }
  }

  // C/D layout: col = lane&15 (n), row = quad*4 + reg (within wave's 16 rows)
  if constexpr (EPI == 1) {
    float* P = Cf + (size_t)blockIdx.z * ((size_t)M * N);
#pragma unroll
    for (int nt = 0; nt < 4; ++nt) {
      int n = bn + nt * 16 + ml;
#pragma unroll
      for (int i = 0; i < 4; ++i) {
        int m = bm + wv * 16 + quad * 4 + i;
        P[(size_t)m * N + n] = acc[nt][i];
      }
    }
  } else if constexpr (EPI == 0) {
#pragma unroll
    for (int nt = 0; nt < 4; ++nt) {
      int n = bn + nt * 16 + ml;
      float bv = bias ? bias[n] : 0.0f;
#pragma unroll
      for (int i = 0; i < 4; ++i) {
        int m = bm + wv * 16 + quad * 4 + i;
        Cf[(size_t)m * N + n] = acc[nt][i] + bv;
      }
    }
  } else if constexpr (EPI == 2) {
#pragma unroll
    for (int nt = 0; nt < 4; ++nt) {
      int n = bn + nt * 16 + ml;
      float bv = bias[n];
#pragma unroll
      for (int i = 0; i < 4; ++i) {
        int m = bm + wv * 16 + quad * 4 + i;
        float v = acc[nt][i] + bv;
        v = v > 0.0f ? v : 0.0f;
        short hh, ll; split1(v, hh, ll);
        Chi[(size_t)m * N + n] = hh;
        Clo[(size_t)m * N + n] = ll;
      }
    }
  } else {  // EPI == 3: conv epilogue, rows quad*4+i pair up for maxpool2
    int m0 = bm + wv * 16 + quad * 4;
    int bb = m0 >> 8;
    int lb = m0 & 255;
    size_t row0 = ((size_t)bb * 128 + (lb >> 1)) * 256;
#pragma unroll
    for (int nt = 0; nt < 4; ++nt) {
      int n = bn + nt * 16 + ml;
      float bv = bias[n];
      float v0 = fmaxf(acc[nt][0] + bv, 0.0f);
      float v1 = fmaxf(acc[nt][1] + bv, 0.0f);
      float v2 = fmaxf(acc[nt][2] + bv, 0.0f);
      float v3 = fmaxf(acc[nt][3] + bv, 0.0f);
      float p0 = fmaxf(v0, v1), p1 = fmaxf(v2, v3);
      short hh, ll;
      split1(p0, hh, ll);
      Chi[row0 + n] = hh; Clo[row0 + n] = ll;
      split1(p1, hh, ll);
      Chi[row0 + 256 + n] = hh; Clo[row0 + 256 + n] = ll;
    }
  }
}

// ---------------------------------------------------------------------------
// split-K reduce + bias + relu + pre-split (enc1). N must be pow2 (2048).
// ---------------------------------------------------------------------------
__global__ __launch_bounds__(256) void reduce_k(const float* __restrict__ P,
                                                const float* __restrict__ bias,
                                                short* __restrict__ hhi,
                                                short* __restrict__ hlo,
                                                int MN, int N, int S) {
  int i = blockIdx.x * 256 + threadIdx.x;
  if (i >= MN) return;
  float s = 0.0f;
  for (int z = 0; z < S; ++z) s += P[(size_t)z * MN + i];
  s += bias[i & (N - 1)];
  s = s > 0.0f ? s : 0.0f;
  short hh, ll; split1(s, hh, ll);
  hhi[i] = hh; hlo[i] = ll;
}

// ---------------------------------------------------------------------------
// depthwise causal conv4 + SiLU on u = xz[:, :512] -> u2 (f32: scan + x_proj)
// ---------------------------------------------------------------------------
__global__ __launch_bounds__(512) void dwconv_k(const float* __restrict__ xz,
                                                const float* __restrict__ cw,
                                                const float* __restrict__ cb,
                                                float* __restrict__ u2) {
  int m = blockIdx.x;                  // b*128 + t
  int t = m & (LP_ - 1);
  int d = threadIdx.x;
  float4 w = *(const float4*)(cw + d * 4);
  const float* base = xz + (size_t)m * (2 * DI_) + d;
  float pre = cb[d];
  if (t >= 3) {
    pre = fmaf(base[-3 * 2 * DI_], w.x, pre);
    pre = fmaf(base[-2 * 2 * DI_], w.y, pre);
    pre = fmaf(base[-1 * 2 * DI_], w.z, pre);
    pre = fmaf(base[0],            w.w, pre);
  } else {
    const float wv[4] = {w.x, w.y, w.z, w.w};
    for (int j = 0; j < 4; ++j) {
      int tt = t - 3 + j;
      if (tt >= 0) pre = fmaf(base[(j - 3) * 2 * DI_], wv[j], pre);
    }
  }
  float s = pre / (1.0f + __expf(-pre));  // silu
  u2[(size_t)m * DI_ + d] = s;
}

// ---------------------------------------------------------------------------
// selective scan, delta fused: phase 1 precomputes softplus(dt@dtw.T+b) for
// the block's 16 channels x 128 t into LDS (work distributed, no redundancy);
// phase 2: 16 lanes per (b,d) channel, one lane per state n, shfl reduce.
// Emits yg pre-split bf16 for out_proj.
// ---------------------------------------------------------------------------
__global__ __launch_bounds__(256) void scan_k(const float* __restrict__ u2,
                                              const float* __restrict__ xz,
                                              const float* __restrict__ xdbl,
                                              const float* __restrict__ dtw,
                                              const float* __restrict__ dtb,
                                              const float* __restrict__ A_log,
                                              const float* __restrict__ Dp,
                                              short* __restrict__ yghi,
                                              short* __restrict__ yglo) {
  __shared__ float dls[16][128];
  const int tid = threadIdx.x;
  const int b = blockIdx.x >> 5;             // 32 blocks per batch row
  const int d0 = (blockIdx.x & 31) << 4;
  const size_t mBase = (size_t)b * LP_;

  {  // phase 1: delta for 16 channels x 128 t (8 t per thread)
    const int ch = tid >> 4;
    const int t0 = (tid & 15) * 8;
    const int d = d0 + ch;
    const float4* wr = (const float4*)(dtw + d * 16);
    float4 w0 = wr[0], w1 = wr[1], w2 = wr[2], w3 = wr[3];
    float bdt = dtb[d];
#pragma unroll
    for (int j = 0; j < 8; ++j) {
      int t = t0 + j;
      const float4* xr = (const float4*)(xdbl + (mBase + t) * 64);
      float4 x0 = xr[0], x1 = xr[1], x2 = xr[2], x3 = xr[3];
      float a = bdt;
      a = fmaf(w0.x, x0.x, a); a = fmaf(w0.y, x0.y, a);
      a = fmaf(w0.z, x0.z, a); a = fmaf(w0.w, x0.w, a);
      a = fmaf(w1.x, x1.x, a); a = fmaf(w1.y, x1.y, a);
      a = fmaf(w1.z, x1.z, a); a = fmaf(w1.w, x1.w, a);
      a = fmaf(w2.x, x2.x, a); a = fmaf(w2.y, x2.y, a);
      a = fmaf(w2.z, x2.z, a); a = fmaf(w2.w, x2.w, a);
      a = fmaf(w3.x, x3.x, a); a = fmaf(w3.y, x3.y, a);
      a = fmaf(w3.z, x3.z, a); a = fmaf(w3.w, x3.w, a);
      float sp = fmaxf(a, 0.0f) + log1pf(__expf(-fabsf(a)));  // softplus
      dls[ch][t] = sp;
    }
  }
  __syncthreads();

  const int n = tid & 15;                    // state index
  const int ch = tid >> 4;
  const int d = d0 + ch;
  float An = -__expf(A_log[d * 16 + n]);
  float Dd = Dp[d];
  float h = 0.0f;
  for (int t = 0; t < LP_; ++t) {
    size_t m = mBase + t;
    float dl = dls[ch][t];
    float uu = u2[m * DI_ + d];
    float Bn = xdbl[m * 64 + 16 + n];
    float Cn = xdbl[m * 64 + 32 + n];
    float dA = __expf(dl * An);
    h = fmaf(dA, h, (dl * uu) * Bn);
    float y = h * Cn;
    y += __shfl_xor(y, 1, 16);
    y += __shfl_xor(y, 2, 16);
    y += __shfl_xor(y, 4, 16);
    y += __shfl_xor(y, 8, 16);
    if (n == 0) {
      float zz = xz[m * (2 * DI_) + DI_ + d];
      float g = zz / (1.0f + __expf(-zz));
      float yv = fmaf(uu, Dd, y) * g;
      short hh, ll; split1(yv, hh, ll);
      yghi[m * DI_ + d] = hh;
      yglo[m * DI_ + d] = ll;
    }
  }
}

// ---------------------------------------------------------------------------
// mean over t + fc head -> out (64, 10)
// ---------------------------------------------------------------------------
__global__ __launch_bounds__(256) void meanfc_k(const float* __restrict__ mout,
                                                const float* __restrict__ fcw,
                                                const float* __restrict__ fcb,
                                                float* __restrict__ out) {
  __shared__ float pooled[256];
  int b = blockIdx.x;
  int c = threadIdx.x;
  float s = 0.0f;
  for (int t = 0; t < LP_; ++t) s += mout[((size_t)b * LP_ + t) * C_ + c];
  pooled[c] = s * (1.0f / 128.0f);
  __syncthreads();
  if (c < 10) {
    float acc = fcb[c];
    for (int k = 0; k < 256; ++k) acc = fmaf(pooled[k], fcw[c * 256 + k], acc);
    out[b * 10 + c] = acc;
  }
}

// ---------------------------------------------------------------------------
extern "C" void kernel_launch(void* const* d_in, const int* in_sizes, int n_in,
                              void* d_out, int out_size, void* d_ws, size_t ws_size,
                              hipStream_t stream) {
  const int*   x         = (const int*)d_in[0];
  const float* embed     = (const float*)d_in[1];
  const float* enc_w1    = (const float*)d_in[2];
  const float* enc_b1    = (const float*)d_in[3];
  const float* enc_w2    = (const float*)d_in[4];
  const float* enc_b2    = (const float*)d_in[5];
  const float* conv_w    = (const float*)d_in[6];
  const float* conv_b    = (const float*)d_in[7];
  const float* in_proj_w = (const float*)d_in[8];
  const float* conv1d_w  = (const float*)d_in[9];
  const float* conv1d_b  = (const float*)d_in[10];
  const float* x_proj_w  = (const float*)d_in[11];
  const float* dt_proj_w = (const float*)d_in[12];
  const float* dt_proj_b = (const float*)d_in[13];
  const float* A_log     = (const float*)d_in[14];
  const float* Dp        = (const float*)d_in[15];
  const float* out_proj_w= (const float*)d_in[16];
  const float* fc_w      = (const float*)d_in[17];
  const float* fc_b      = (const float*)d_in[18];
  float* out = (float*)d_out;

  char* ws = (char*)d_ws;
  size_t off = 0;
  auto alloc = [&](size_t bytes) {
    char* p = ws + off;
    off += (bytes + 255) & ~(size_t)255;
    return p;
  };
  short* ehi   = (short*)alloc(2097152ull * 2);   // e hi/lo (64, 32768)
  short* elo   = (short*)alloc(2097152ull * 2);
  float* P     = (float*)alloc(4194304ull * 4);   // split-K partials (32,64,2048)
  short* h1hi  = (short*)alloc(131072ull  * 2);   // (64, 2048)
  short* h1lo  = (short*)alloc(131072ull  * 2);
  short* h2hi  = (short*)alloc(2097152ull * 2);   // (64, 32768)
  short* h2lo  = (short*)alloc(2097152ull * 2);
  short* wthi  = (short*)alloc(163840ull  * 2);   // conv W (256, 640)
  short* wtlo  = (short*)alloc(163840ull  * 2);
  short* ipwhi = (short*)alloc(262144ull  * 2);   // in_proj_w (1024, 256)
  short* ipwlo = (short*)alloc(262144ull  * 2);
  short* xpwhi = (short*)alloc(32768ull   * 2);   // x_proj_w padded (64, 512)
  short* xpwlo = (short*)alloc(32768ull   * 2);
  short* opwhi = (short*)alloc(131072ull  * 2);   // out_proj_w (256, 512)
  short* opwlo = (short*)alloc(131072ull  * 2);
  short* xshi  = (short*)alloc(2097152ull * 2);   // xs (8192, 256)
  short* xslo  = (short*)alloc(2097152ull * 2);
  float* xz    = (float*)alloc(8388608ull * 4);   // (8192, 1024)
  float* u2    = (float*)alloc(4194304ull * 4);   // (8192, 512)
  float* xdbl  = (float*)alloc(524288ull  * 4);   // (8192, 64)
  short* yghi  = (short*)alloc(4194304ull * 2);   // yg (8192, 512)
  short* yglo  = (short*)alloc(4194304ull * 2);
  float* mout  = (float*)alloc(2097152ull * 4);   // (8192, 256)
  (void)ws_size; (void)in_sizes; (void)n_in; (void)out_size;

  prep_all<<<2304, 256, 0, stream>>>(conv_w, in_proj_w, out_proj_w, x_proj_w,
                                     wthi, wtlo, ipwhi, ipwlo, opwhi, opwlo,
                                     xpwhi, xpwlo);
  embed_k<<<4096, 256, 0, stream>>>(x, embed, ehi, elo);

  // enc1: (64,2048,K=32768), split-K=32 -> 1024 blocks
  gemm_t<1, 0, 1><<<dim3(32, 1, 32), 256, 0, stream>>>(
      ehi, elo, enc_w1, nullptr, nullptr, P, nullptr, nullptr,
      64, 2048, 32768, 1024);
  reduce_k<<<512, 256, 0, stream>>>(P, enc_b1, h1hi, h1lo, 131072, 2048, 32);

  // enc2: (64,32768,K=2048), bias+relu+presplit fused
  gemm_t<1, 0, 2><<<dim3(512, 1, 1), 256, 0, stream>>>(
      h1hi, h1lo, enc_w2, nullptr, enc_b2, nullptr, h2hi, h2lo,
      64, 32768, 2048, 2048);

  // conv as GEMM: (16384,256,K=640) with shifted gather + pool epilogue
  gemm_t<2, 1, 3><<<dim3(4, 256, 1), 256, 0, stream>>>(
      h2hi, h2lo, wthi, wtlo, conv_b, nullptr, xshi, xslo,
      16384, 256, 640, 640);

  // in_proj: (8192,1024,K=256)
  gemm_t<1, 1, 0><<<dim3(16, 128, 1), 256, 0, stream>>>(
      xshi, xslo, ipwhi, ipwlo, nullptr, xz, nullptr, nullptr,
      8192, 1024, 256, 256);

  dwconv_k<<<8192, 512, 0, stream>>>(xz, conv1d_w, conv1d_b, u2);

  // x_proj (padded to N=64): (8192,64,K=512)
  gemm_t<0, 1, 0><<<dim3(1, 128, 1), 256, 0, stream>>>(
      u2, nullptr, xpwhi, xpwlo, nullptr, xdbl, nullptr, nullptr,
      8192, 64, 512, 512);

  // scan with fused delta, emits pre-split yg
  scan_k<<<2048, 256, 0, stream>>>(u2, xz, xdbl, dt_proj_w, dt_proj_b,
                                   A_log, Dp, yghi, yglo);

  // out_proj: (8192,256,K=512)
  gemm_t<1, 1, 0><<<dim3(4, 128, 1), 256, 0, stream>>>(
      yghi, yglo, opwhi, opwlo, nullptr, mout, nullptr, nullptr,
      8192, 256, 512, 512);

  meanfc_k<<<64, 256, 0, stream>>>(mout, fc_w, fc_b, out);
}

// Round 2
// 839.723 us; speedup vs baseline: 1.1476x; 1.1476x over previous
//
#include <hip/hip_runtime.h>
#include <cstddef>
#include <cstdint>

// Problem constants
#define B_   64
#define L_   256
#define E_   128
#define H_   2048
#define C_   256
#define LP_  128      // L/2 after maxpool
#define DI_  512      // d_inner
#define DS_  16       // d_state

typedef __attribute__((ext_vector_type(8))) short s16x8;
typedef __attribute__((ext_vector_type(4))) float f32x4;

// ---------------------------------------------------------------------------
// bf16 split helpers: x = hi + lo, both bf16. Hardware packed convert.
// ---------------------------------------------------------------------------
__device__ __forceinline__ uint32_t cvt_pk_bf16(float a, float b) {
  uint32_t r;
  asm("v_cvt_pk_bf16_f32 %0, %1, %2" : "=v"(r) : "v"(a), "v"(b));
  return r;  // low short = bf16(a), high short = bf16(b)
}

__device__ __forceinline__ void split1(float x, short& h, short& l) {
  uint32_t p = cvt_pk_bf16(x, x);
  float rres = x - __uint_as_float(p << 16);
  uint32_t q = cvt_pk_bf16(rres, rres);
  h = (short)p; l = (short)q;
}

// 8 floats -> hi/lo bf16x8 (6 VALU inst per 2 floats)
__device__ __forceinline__ void cvt8(const float4& a0, const float4& a1,
                                     s16x8& h, s16x8& l) {
  union { uint32_t u[4]; s16x8 v; } H, L;
  float x[8] = {a0.x, a0.y, a0.z, a0.w, a1.x, a1.y, a1.z, a1.w};
#pragma unroll
  for (int j = 0; j < 4; ++j) {
    uint32_t p = cvt_pk_bf16(x[2*j], x[2*j+1]);
    float r0 = x[2*j]   - __uint_as_float(p << 16);
    float r1 = x[2*j+1] - __uint_as_float(p & 0xFFFF0000u);
    H.u[j] = p;
    L.u[j] = cvt_pk_bf16(r0, r1);
  }
  h = H.v; l = L.v;
}

// ---------------------------------------------------------------------------
// embed gather -> pre-split bf16 hi/lo  (e[b,l*E+j] = embed[x[b,l], j])
// ---------------------------------------------------------------------------
__global__ __launch_bounds__(256) void embed_k(const int* __restrict__ x,
                                               const float* __restrict__ emb,
                                               short* __restrict__ ehi,
                                               short* __restrict__ elo) {
  int bl = blockIdx.x * 4 + (threadIdx.x >> 6);
  int lane = threadIdx.x & 63;
  int idx = x[bl];
  float2 v = ((const float2*)(emb + (size_t)idx * E_))[lane];
  uint32_t p = cvt_pk_bf16(v.x, v.y);
  float r0 = v.x - __uint_as_float(p << 16);
  float r1 = v.y - __uint_as_float(p & 0xFFFF0000u);
  uint32_t q = cvt_pk_bf16(r0, r1);
  ((uint32_t*)ehi)[(size_t)bl * 64 + lane] = p;
  ((uint32_t*)elo)[(size_t)bl * 64 + lane] = q;
}

// ---------------------------------------------------------------------------
// one-shot weight preps: conv wT (c,k=t*128+e), in_proj_w, out_proj_w,
// x_proj_w (padded 48->64 rows) -> all pre-split bf16 hi/lo
// ---------------------------------------------------------------------------
__global__ __launch_bounds__(256) void prep_all(
    const float* __restrict__ conv_w, const float* __restrict__ ipw,
    const float* __restrict__ opw,    const float* __restrict__ xpw,
    short* __restrict__ wthi,  short* __restrict__ wtlo,
    short* __restrict__ ipwhi, short* __restrict__ ipwlo,
    short* __restrict__ opwhi, short* __restrict__ opwlo,
    short* __restrict__ xpwhi, short* __restrict__ xpwlo) {
  int blk = blockIdx.x, tid = threadIdx.x;
  if (blk < 640) {                       // conv: k = blk (t*128+e), c = tid
    int k = blk, c = tid, t = k >> 7, e = k & 127;
    float v = conv_w[c * 640 + e * 5 + t];
    short h, l; split1(v, h, l);
    wthi[(size_t)c * 640 + k] = h; wtlo[(size_t)c * 640 + k] = l;
  } else if (blk < 640 + 1024) {         // in_proj_w (1024 x 256)
    int n = blk - 640;
    size_t i = (size_t)n * 256 + tid;
    short h, l; split1(ipw[i], h, l);
    ipwhi[i] = h; ipwlo[i] = l;
  } else if (blk < 640 + 1024 + 512) {   // out_proj_w (256 x 512)
    size_t i = (size_t)(blk - 1664) * 256 + tid;
    short h, l; split1(opw[i], h, l);
    opwhi[i] = h; opwlo[i] = l;
  } else {                               // x_proj_w padded to (64 x 512)
    int i = (blk - 2176) * 256 + tid;    // 0..32767
    int n = i >> 9, k = i & 511;
    float v = (n < 48) ? xpw[n * 512 + k] : 0.0f;
    short h, l; split1(v, h, l);
    xpwhi[i] = h; xpwlo[i] = l;
  }
}

// ---------------------------------------------------------------------------
// MFMA split-bf16 GEMM: C[m,n] = sum_k A[m,k] * W[n,k]
// acc += Ahi*Whi + Ahi*Wlo + Alo*Whi  (3 MFMA per K=32 step)
// BM=BN=64, BK=32, 256 threads = 4 waves, wave tile 16(M)x64(N).
// AM: 0 = f32 A (convert in-kernel), 1 = pre-split bf16 A, 2 = conv gather
//     from pre-split h2 with t-shift + zero pad.
// WM: 0 = f32 W (convert in-kernel), 1 = pre-split bf16 W.
// EPI: 0 = f32 out (+opt bias); 1 = split-K f32 partial; 2 = bias+relu+
//      pre-split out; 3 = conv epilogue bias+relu+maxpool2+pre-split out.
// ---------------------------------------------------------------------------
template<int AM, int WM, int EPI>
__global__ __launch_bounds__(256) void gemm_t(
    const void* __restrict__ Aa, const void* __restrict__ Ab,
    const void* __restrict__ Wa, const void* __restrict__ Wb,
    const float* __restrict__ bias,
    float* __restrict__ Cf, short* __restrict__ Chi, short* __restrict__ Clo,
    int M, int N, int K, int kChunk) {
  // stride 40 shorts = 80 B (16B-aligned rows, <=2-way banks on frag reads)
  __shared__ __align__(16) short AhiS[64][40];
  __shared__ __align__(16) short AloS[64][40];
  __shared__ __align__(16) short WhiS[64][40];
  __shared__ __align__(16) short WloS[64][40];

  const int tid = threadIdx.x;
  const int r   = tid >> 2;                  // staging row 0..63
  const int seg = (tid & 3) * 8;             // staging k-seg 0/8/16/24
  const int lane = tid & 63;
  const int wv   = tid >> 6;                 // wave 0..3 -> M-strip
  const int ml   = lane & 15;
  const int quad = lane >> 4;
  const int bn = blockIdx.x * 64, bm = blockIdx.y * 64;
  const int kStart = blockIdx.z * kChunk, kEnd = kStart + kChunk;

  f32x4 acc[4];
#pragma unroll
  for (int nt = 0; nt < 4; ++nt) acc[nt] = (f32x4){0.f, 0.f, 0.f, 0.f};

  auto loadA = [&](int k0, s16x8& h, s16x8& l) {
    if constexpr (AM == 0) {
      const float* Ar = (const float*)Aa + (size_t)(bm + r) * K + seg + k0;
      float4 a0 = *(const float4*)Ar;
      float4 a1 = *(const float4*)(Ar + 4);
      cvt8(a0, a1, h, l);
    } else if constexpr (AM == 1) {
      size_t o = (size_t)(bm + r) * K + seg + k0;
      h = *(const s16x8*)((const short*)Aa + o);
      l = *(const s16x8*)((const short*)Ab + o);
    } else {  // conv gather from h2 (64 x 256 x 128), k = t*128+e
      int m = bm + r, bb = m >> 8, lrow = m & 255;
      int k = k0 + seg, t = k >> 7, e = k & 127;
      int ls = lrow + t - 2;
      if (ls >= 0 && ls < 256) {
        size_t o = ((size_t)bb << 15) + ((size_t)ls << 7) + (size_t)e;
        h = *(const s16x8*)((const short*)Aa + o);
        l = *(const s16x8*)((const short*)Ab + o);
      } else {
        h = (s16x8)(short)0; l = (s16x8)(short)0;
      }
    }
  };
  auto loadW = [&](int k0, s16x8& h, s16x8& l) {
    if constexpr (WM == 0) {
      const float* Wr = (const float*)Wa + (size_t)(bn + r) * K + seg + k0;
      float4 w0 = *(const float4*)Wr;
      float4 w1 = *(const float4*)(Wr + 4);
      cvt8(w0, w1, h, l);
    } else {
      size_t o = (size_t)(bn + r) * K + seg + k0;
      h = *(const s16x8*)((const short*)Wa + o);
      l = *(const s16x8*)((const short*)Wb + o);
    }
  };

  s16x8 pAh, pAl, pWh, pWl;
  loadA(kStart, pAh, pAl);
  loadW(kStart, pWh, pWl);

  for (int k0 = kStart; k0 < kEnd; k0 += 32) {
    __syncthreads();   // previous iteration's frag reads done
    *(s16x8*)&AhiS[r][seg] = pAh;
    *(s16x8*)&AloS[r][seg] = pAl;
    *(s16x8*)&WhiS[r][seg] = pWh;
    *(s16x8*)&WloS[r][seg] = pWl;
    __syncthreads();
    if (k0 + 32 < kEnd) {                    // prefetch next K-tile
      loadA(k0 + 32, pAh, pAl);
      loadW(k0 + 32, pWh, pWl);
    }
    s16x8 fah = *(const s16x8*)&AhiS[wv * 16 + ml][quad * 8];
    s16x8 fal = *(const s16x8*)&AloS[wv * 16 + ml][quad * 8];
#pragma unroll
    for (int nt = 0; nt < 4; ++nt) {
      s16x8 fwh = *(const s16x8*)&WhiS[nt * 16 + ml][quad * 8];
      s16x8 fwl = *(const s16x8*)&WloS[nt * 16 + ml][quad * 8];
      acc[nt] = __builtin_amdgcn_mfma_f32_16x16x32_bf16(fah, fwh, acc[nt], 0, 0, 0);
      acc[nt] = __builtin_amdgcn_mfma_f32_16x16x32_bf16(fah, fwl, acc[nt], 0, 0, 0);
      acc[nt] = __builtin_amdgcn_mfma_f32_16x16x32_bf16(fal, fwh, acc[nt], 0, 0, 0);
    }
  }

  // C/D layout: col = lane&15 (n), row = quad*4 + reg (within wave's 16 rows)
  if constexpr (EPI == 1) {
    float* P = Cf + (size_t)blockIdx.z * ((size_t)M * N);
#pragma unroll
    for (int nt = 0; nt < 4; ++nt) {
      int n = bn + nt * 16 + ml;
#pragma unroll
      for (int i = 0; i < 4; ++i) {
        int m = bm + wv * 16 + quad * 4 + i;
        P[(size_t)m * N + n] = acc[nt][i];
      }
    }
  } else if constexpr (EPI == 0) {
#pragma unroll
    for (int nt = 0; nt < 4; ++nt) {
      int n = bn + nt * 16 + ml;
      float bv = bias ? bias[n] : 0.0f;
#pragma unroll
      for (int i = 0; i < 4; ++i) {
        int m = bm + wv * 16 + quad * 4 + i;
        Cf[(size_t)m * N + n] = acc[nt][i] + bv;
      }
    }
  } else if constexpr (EPI == 2) {
#pragma unroll
    for (int nt = 0; nt < 4; ++nt) {
      int n = bn + nt * 16 + ml;
      float bv = bias[n];
#pragma unroll
      for (int i = 0; i < 4; ++i) {
        int m = bm + wv * 16 + quad * 4 + i;
        float v = acc[nt][i] + bv;
        v = v > 0.0f ? v : 0.0f;
        short hh, ll; split1(v, hh, ll);
        Chi[(size_t)m * N + n] = hh;
        Clo[(size_t)m * N + n] = ll;
      }
    }
  } else {  // EPI == 3: conv epilogue, rows quad*4+i pair up for maxpool2
    int m0 = bm + wv * 16 + quad * 4;
    int bb = m0 >> 8;
    int lb = m0 & 255;
    size_t row0 = ((size_t)bb * 128 + (lb >> 1)) * 256;
#pragma unroll
    for (int nt = 0; nt < 4; ++nt) {
      int n = bn + nt * 16 + ml;
      float bv = bias[n];
      float v0 = fmaxf(acc[nt][0] + bv, 0.0f);
      float v1 = fmaxf(acc[nt][1] + bv, 0.0f);
      float v2 = fmaxf(acc[nt][2] + bv, 0.0f);
      float v3 = fmaxf(acc[nt][3] + bv, 0.0f);
      float p0 = fmaxf(v0, v1), p1 = fmaxf(v2, v3);
      short hh, ll;
      split1(p0, hh, ll);
      Chi[row0 + n] = hh; Clo[row0 + n] = ll;
      split1(p1, hh, ll);
      Chi[row0 + 256 + n] = hh; Clo[row0 + 256 + n] = ll;
    }
  }
}

// ---------------------------------------------------------------------------
// split-K reduce + bias + relu + pre-split (enc1). N must be pow2 (2048).
// ---------------------------------------------------------------------------
__global__ __launch_bounds__(256) void reduce_k(const float* __restrict__ P,
                                                const float* __restrict__ bias,
                                                short* __restrict__ hhi,
                                                short* __restrict__ hlo,
                                                int MN, int N, int S) {
  int i = blockIdx.x * 256 + threadIdx.x;
  if (i >= MN) return;
  float s = 0.0f;
  for (int z = 0; z < S; ++z) s += P[(size_t)z * MN + i];
  s += bias[i & (N - 1)];
  s = s > 0.0f ? s : 0.0f;
  short hh, ll; split1(s, hh, ll);
  hhi[i] = hh; hlo[i] = ll;
}

// ---------------------------------------------------------------------------
// depthwise causal conv4 + SiLU on u = xz[:, :512] -> u2 (f32: scan + x_proj)
// ---------------------------------------------------------------------------
__global__ __launch_bounds__(512) void dwconv_k(const float* __restrict__ xz,
                                                const float* __restrict__ cw,
                                                const float* __restrict__ cb,
                                                float* __restrict__ u2) {
  int m = blockIdx.x;                  // b*128 + t
  int t = m & (LP_ - 1);
  int d = threadIdx.x;
  float4 w = *(const float4*)(cw + d * 4);
  const float* base = xz + (size_t)m * (2 * DI_) + d;
  float pre = cb[d];
  if (t >= 3) {
    pre = fmaf(base[-3 * 2 * DI_], w.x, pre);
    pre = fmaf(base[-2 * 2 * DI_], w.y, pre);
    pre = fmaf(base[-1 * 2 * DI_], w.z, pre);
    pre = fmaf(base[0],            w.w, pre);
  } else {
    const float wv[4] = {w.x, w.y, w.z, w.w};
    for (int j = 0; j < 4; ++j) {
      int tt = t - 3 + j;
      if (tt >= 0) pre = fmaf(base[(j - 3) * 2 * DI_], wv[j], pre);
    }
  }
  float s = pre / (1.0f + __expf(-pre));  // silu
  u2[(size_t)m * DI_ + d] = s;
}

// ---------------------------------------------------------------------------
// selective scan, delta fused. Block = (b, 16-channel group), 256 thr.
// Phase 1: delta -> LDS (padded [16][132], conflict-free).
// Main: 4 chunks of 32 t, double-buffered LDS staging of u2/B/C/z
// (T14 async-split: issue loads -> compute -> ds_write), batched-8 shfl
// reduce, LDS-gathered coalesced bf16 output writes.
// ---------------------------------------------------------------------------
__global__ __launch_bounds__(256) void scan_k(const float* __restrict__ u2,
                                              const float* __restrict__ xz,
                                              const float* __restrict__ xdbl,
                                              const float* __restrict__ dtw,
                                              const float* __restrict__ dtb,
                                              const float* __restrict__ A_log,
                                              const float* __restrict__ Dp,
                                              short* __restrict__ yghi,
                                              short* __restrict__ yglo) {
  __shared__ float dls[16][132];                  // delta, padded stride
  __shared__ __align__(16) float u2s[2][32][16];  // u tile
  __shared__ __align__(16) float zs [2][32][16];  // z tile
  __shared__ __align__(16) float bcs[2][32][32];  // B|C tile
  __shared__ short ygs_hi[32][16];                // gated output gather
  __shared__ short ygs_lo[32][16];

  const int tid = threadIdx.x;
  const int b = blockIdx.x >> 5;             // 32 blocks per batch row
  const int d0 = (blockIdx.x & 31) << 4;
  const size_t mBase = (size_t)b * LP_;

  {  // phase 1: delta for 16 channels x 128 t (8 t per thread, t strided 16)
    const int ch = tid >> 4;
    const int tl = tid & 15;
    const int d = d0 + ch;
    const float4* wr = (const float4*)(dtw + d * 16);
    float4 w0 = wr[0], w1 = wr[1], w2 = wr[2], w3 = wr[3];
    float bdt = dtb[d];
#pragma unroll
    for (int j = 0; j < 8; ++j) {
      int t = tl + 16 * j;
      const float4* xr = (const float4*)(xdbl + (mBase + t) * 64);
      float4 x0 = xr[0], x1 = xr[1], x2 = xr[2], x3 = xr[3];
      float a = bdt;
      a = fmaf(w0.x, x0.x, a); a = fmaf(w0.y, x0.y, a);
      a = fmaf(w0.z, x0.z, a); a = fmaf(w0.w, x0.w, a);
      a = fmaf(w1.x, x1.x, a); a = fmaf(w1.y, x1.y, a);
      a = fmaf(w1.z, x1.z, a); a = fmaf(w1.w, x1.w, a);
      a = fmaf(w2.x, x2.x, a); a = fmaf(w2.y, x2.y, a);
      a = fmaf(w2.z, x2.z, a); a = fmaf(w2.w, x2.w, a);
      a = fmaf(w3.x, x3.x, a); a = fmaf(w3.y, x3.y, a);
      a = fmaf(w3.z, x3.z, a); a = fmaf(w3.w, x3.w, a);
      float sp = fmaxf(a, 0.0f) + log1pf(__expf(-fabsf(a)));  // softplus
      dls[ch][t] = sp;
    }
  }

  // stage chunk 0 (buffer 0)
  const int stt = tid >> 3;                  // 0..31 (t within chunk)
  const int sjj = tid & 7;                   // 0..7
  {
    size_t m = mBase + stt;
    float2 ru  = *(const float2*)(u2 + m * DI_ + d0 + sjj * 2);
    float2 rz  = *(const float2*)(xz + m * (2 * DI_) + DI_ + d0 + sjj * 2);
    float4 rbc = *(const float4*)(xdbl + m * 64 + 16 + sjj * 4);
    *(float2*)&u2s[0][stt][sjj * 2] = ru;
    *(float2*)&zs [0][stt][sjj * 2] = rz;
    *(float4*)&bcs[0][stt][sjj * 4] = rbc;
  }

  const int n  = tid & 15;                   // state index
  const int ch = tid >> 4;                   // channel within block
  const int d  = d0 + ch;
  float An = -__expf(A_log[d * 16 + n]);
  float Dd = Dp[d];
  float h = 0.0f;

  for (int c = 0; c < 4; ++c) {
    const int buf = c & 1;
    __syncthreads();                         // staged chunk c visible
    float2 ru, rz; float4 rbc;               // issue loads for chunk c+1
    const bool pre = (c < 3);
    if (pre) {
      size_t m = mBase + (c + 1) * 32 + stt;
      ru  = *(const float2*)(u2 + m * DI_ + d0 + sjj * 2);
      rz  = *(const float2*)(xz + m * (2 * DI_) + DI_ + d0 + sjj * 2);
      rbc = *(const float4*)(xdbl + m * 64 + 16 + sjj * 4);
    }
    float y[8];
#pragma unroll
    for (int tb = 0; tb < 32; tb += 8) {
#pragma unroll
      for (int j = 0; j < 8; ++j) {
        int tt = tb + j;
        float dl = dls[ch][c * 32 + tt];
        float uu = u2s[buf][tt][ch];
        float Bn = bcs[buf][tt][n];
        float Cn = bcs[buf][tt][16 + n];
        float dA = __expf(dl * An);
        h = fmaf(dA, h, (dl * uu) * Bn);
        y[j] = h * Cn;
      }
      // batched reduce over n: 8 independent 4-level chains
#pragma unroll
      for (int s = 1; s < 16; s <<= 1) {
#pragma unroll
        for (int j = 0; j < 8; ++j) y[j] += __shfl_xor(y[j], s, 16);
      }
      // every lane now holds all 8 sums; lane n<8 handles t = tb+n
      float my = y[0];
#pragma unroll
      for (int j = 1; j < 8; ++j) my = (n == j) ? y[j] : my;
      if (n < 8) {
        int tt = tb + n;
        float uu = u2s[buf][tt][ch];
        float zz = zs[buf][tt][ch];
        float g = zz / (1.0f + __expf(-zz));
        float yv = fmaf(uu, Dd, my) * g;
        short hh, ll; split1(yv, hh, ll);
        ygs_hi[tt][ch] = hh;
        ygs_lo[tt][ch] = ll;
      }
    }
    __syncthreads();                         // ygs complete (cross-wave)
    {  // coalesced output: 32B per (t, 16ch) row
      size_t m = mBase + c * 32 + stt;
      ((uint32_t*)(yghi + m * DI_ + d0))[sjj] = *(uint32_t*)&ygs_hi[stt][sjj * 2];
      ((uint32_t*)(yglo + m * DI_ + d0))[sjj] = *(uint32_t*)&ygs_lo[stt][sjj * 2];
    }
    if (pre) {                               // write staged chunk c+1
      const int nb = buf ^ 1;
      *(float2*)&u2s[nb][stt][sjj * 2] = ru;
      *(float2*)&zs [nb][stt][sjj * 2] = rz;
      *(float4*)&bcs[nb][stt][sjj * 4] = rbc;
    }
  }
}

// ---------------------------------------------------------------------------
// mean over t + fc head -> out (64, 10)
// ---------------------------------------------------------------------------
__global__ __launch_bounds__(256) void meanfc_k(const float* __restrict__ mout,
                                                const float* __restrict__ fcw,
                                                const float* __restrict__ fcb,
                                                float* __restrict__ out) {
  __shared__ float pooled[256];
  int b = blockIdx.x;
  int c = threadIdx.x;
  float s = 0.0f;
  for (int t = 0; t < LP_; ++t) s += mout[((size_t)b * LP_ + t) * C_ + c];
  pooled[c] = s * (1.0f / 128.0f);
  __syncthreads();
  if (c < 10) {
    float acc = fcb[c];
    for (int k = 0; k < 256; ++k) acc = fmaf(pooled[k], fcw[c * 256 + k], acc);
    out[b * 10 + c] = acc;
  }
}

// ---------------------------------------------------------------------------
extern "C" void kernel_launch(void* const* d_in, const int* in_sizes, int n_in,
                              void* d_out, int out_size, void* d_ws, size_t ws_size,
                              hipStream_t stream) {
  const int*   x         = (const int*)d_in[0];
  const float* embed     = (const float*)d_in[1];
  const float* enc_w1    = (const float*)d_in[2];
  const float* enc_b1    = (const float*)d_in[3];
  const float* enc_w2    = (const float*)d_in[4];
  const float* enc_b2    = (const float*)d_in[5];
  const float* conv_w    = (const float*)d_in[6];
  const float* conv_b    = (const float*)d_in[7];
  const float* in_proj_w = (const float*)d_in[8];
  const float* conv1d_w  = (const float*)d_in[9];
  const float* conv1d_b  = (const float*)d_in[10];
  const float* x_proj_w  = (const float*)d_in[11];
  const float* dt_proj_w = (const float*)d_in[12];
  const float* dt_proj_b = (const float*)d_in[13];
  const float* A_log     = (const float*)d_in[14];
  const float* Dp        = (const float*)d_in[15];
  const float* out_proj_w= (const float*)d_in[16];
  const float* fc_w      = (const float*)d_in[17];
  const float* fc_b      = (const float*)d_in[18];
  float* out = (float*)d_out;

  char* ws = (char*)d_ws;
  size_t off = 0;
  auto alloc = [&](size_t bytes) {
    char* p = ws + off;
    off += (bytes + 255) & ~(size_t)255;
    return p;
  };
  short* ehi   = (short*)alloc(2097152ull * 2);   // e hi/lo (64, 32768)
  short* elo   = (short*)alloc(2097152ull * 2);
  float* P     = (float*)alloc(4194304ull * 4);   // split-K partials (32,64,2048)
  short* h1hi  = (short*)alloc(131072ull  * 2);   // (64, 2048)
  short* h1lo  = (short*)alloc(131072ull  * 2);
  short* h2hi  = (short*)alloc(2097152ull * 2);   // (64, 32768)
  short* h2lo  = (short*)alloc(2097152ull * 2);
  short* wthi  = (short*)alloc(163840ull  * 2);   // conv W (256, 640)
  short* wtlo  = (short*)alloc(163840ull  * 2);
  short* ipwhi = (short*)alloc(262144ull  * 2);   // in_proj_w (1024, 256)
  short* ipwlo = (short*)alloc(262144ull  * 2);
  short* xpwhi = (short*)alloc(32768ull   * 2);   // x_proj_w padded (64, 512)
  short* xpwlo = (short*)alloc(32768ull   * 2);
  short* opwhi = (short*)alloc(131072ull  * 2);   // out_proj_w (256, 512)
  short* opwlo = (short*)alloc(131072ull  * 2);
  short* xshi  = (short*)alloc(2097152ull * 2);   // xs (8192, 256)
  short* xslo  = (short*)alloc(2097152ull * 2);
  float* xz    = (float*)alloc(8388608ull * 4);   // (8192, 1024)
  float* u2    = (float*)alloc(4194304ull * 4);   // (8192, 512)
  float* xdbl  = (float*)alloc(524288ull  * 4);   // (8192, 64)
  short* yghi  = (short*)alloc(4194304ull * 2);   // yg (8192, 512)
  short* yglo  = (short*)alloc(4194304ull * 2);
  float* mout  = (float*)alloc(2097152ull * 4);   // (8192, 256)
  (void)ws_size; (void)in_sizes; (void)n_in; (void)out_size;

  prep_all<<<2304, 256, 0, stream>>>(conv_w, in_proj_w, out_proj_w, x_proj_w,
                                     wthi, wtlo, ipwhi, ipwlo, opwhi, opwlo,
                                     xpwhi, xpwlo);
  embed_k<<<4096, 256, 0, stream>>>(x, embed, ehi, elo);

  // enc1: (64,2048,K=32768), split-K=32 -> 1024 blocks
  gemm_t<1, 0, 1><<<dim3(32, 1, 32), 256, 0, stream>>>(
      ehi, elo, enc_w1, nullptr, nullptr, P, nullptr, nullptr,
      64, 2048, 32768, 1024);
  reduce_k<<<512, 256, 0, stream>>>(P, enc_b1, h1hi, h1lo, 131072, 2048, 32);

  // enc2: (64,32768,K=2048), bias+relu+presplit fused
  gemm_t<1, 0, 2><<<dim3(512, 1, 1), 256, 0, stream>>>(
      h1hi, h1lo, enc_w2, nullptr, enc_b2, nullptr, h2hi, h2lo,
      64, 32768, 2048, 2048);

  // conv as GEMM: (16384,256,K=640) with shifted gather + pool epilogue
  gemm_t<2, 1, 3><<<dim3(4, 256, 1), 256, 0, stream>>>(
      h2hi, h2lo, wthi, wtlo, conv_b, nullptr, xshi, xslo,
      16384, 256, 640, 640);

  // in_proj: (8192,1024,K=256)
  gemm_t<1, 1, 0><<<dim3(16, 128, 1), 256, 0, stream>>>(
      xshi, xslo, ipwhi, ipwlo, nullptr, xz, nullptr, nullptr,
      8192, 1024, 256, 256);

  dwconv_k<<<8192, 512, 0, stream>>>(xz, conv1d_w, conv1d_b, u2);

  // x_proj (padded to N=64): (8192,64,K=512)
  gemm_t<0, 1, 0><<<dim3(1, 128, 1), 256, 0, stream>>>(
      u2, nullptr, xpwhi, xpwlo, nullptr, xdbl, nullptr, nullptr,
      8192, 64, 512, 512);

  // scan with fused delta, emits pre-split yg
  scan_k<<<2048, 256, 0, stream>>>(u2, xz, xdbl, dt_proj_w, dt_proj_b,
                                   A_log, Dp, yghi, yglo);

  // out_proj: (8192,256,K=512)
  gemm_t<1, 1, 0><<<dim3(4, 128, 1), 256, 0, stream>>>(
      yghi, yglo, opwhi, opwlo, nullptr, mout, nullptr, nullptr,
      8192, 256, 512, 512);

  meanfc_k<<<64, 256, 0, stream>>>(mout, fc_w, fc_b, out);
}